// Round 1
// baseline (985.783 us; speedup 1.0000x reference)
//
#include <hip/hip_runtime.h>

typedef __bf16 bf16_t;
typedef __attribute__((ext_vector_type(8))) __bf16 bf16x8;
typedef __attribute__((ext_vector_type(4))) __bf16 bf16x4;
typedef __attribute__((ext_vector_type(4))) float f32x4;

static constexpr int kB = 2, kT = 2048, kS = 576, kC = 1024, kH = 16, kD = 64;
static constexpr float kScale = 0.125f; // 1/sqrt(64)

#define MFMA16(a, b, c) __builtin_amdgcn_mfma_f32_16x16x32_bf16((a), (b), (c), 0, 0, 0)

__device__ inline float gelu_tanh(float x) {
    float x3 = x * x * x;
    float t = tanhf(0.7978845608028654f * (x + 0.044715f * x3));
    return 0.5f * x * (1.f + t);
}

// ---------------- weight transpose + f32->bf16: W[K,N] -> WT[N,K] ----------------
__global__ void transpose_w(const float* __restrict__ W, bf16_t* __restrict__ WT, int K, int N) {
    __shared__ float tile[32][33];
    int n0 = blockIdx.x * 32, k0 = blockIdx.y * 32;
    int tx = threadIdx.x, ty = threadIdx.y;
#pragma unroll
    for (int i = 0; i < 4; ++i)
        tile[ty + i * 8][tx] = W[(size_t)(k0 + ty + i * 8) * N + n0 + tx];
    __syncthreads();
#pragma unroll
    for (int i = 0; i < 4; ++i)
        WT[(size_t)(n0 + ty + i * 8) * K + k0 + tx] = (bf16_t)tile[tx][ty + i * 8];
}

// ---------------- f32 -> bf16 elementwise (n4 = count/4) ----------------
__global__ void f32_to_bf16(const float* __restrict__ in, bf16_t* __restrict__ out, int n4) {
    int i = blockIdx.x * 256 + threadIdx.x;
    if (i < n4) {
        float4 v = ((const float4*)in)[i];
        bf16x4 o;
        o[0] = (bf16_t)v.x; o[1] = (bf16_t)v.y; o[2] = (bf16_t)v.z; o[3] = (bf16_t)v.w;
        ((bf16x4*)out)[i] = o;
    }
}

// ---------------- LayerNorm: fp32 in [rows, 1024] -> bf16 out ----------------
__global__ __launch_bounds__(256) void ln_kernel(const float* __restrict__ x,
                                                 const float* __restrict__ w,
                                                 const float* __restrict__ bb,
                                                 bf16_t* __restrict__ out) {
    int row = blockIdx.x, tid = threadIdx.x;
    const float* xr = x + (size_t)row * kC;
    float4 v = ((const float4*)xr)[tid];
    float s1 = v.x + v.y + v.z + v.w;
    float s2 = v.x * v.x + v.y * v.y + v.z * v.z + v.w * v.w;
#pragma unroll
    for (int o = 32; o > 0; o >>= 1) {
        s1 += __shfl_down(s1, o);
        s2 += __shfl_down(s2, o);
    }
    __shared__ float red[8];
    __shared__ float mv[2];
    int wid = tid >> 6, lane = tid & 63;
    if (lane == 0) { red[wid] = s1; red[4 + wid] = s2; }
    __syncthreads();
    if (tid == 0) {
        float a = red[0] + red[1] + red[2] + red[3];
        float c = red[4] + red[5] + red[6] + red[7];
        float mean = a * (1.f / kC);
        float var = c * (1.f / kC) - mean * mean;
        mv[0] = mean;
        mv[1] = rsqrtf(var + 1e-5f);
    }
    __syncthreads();
    float mean = mv[0], rstd = mv[1];
    float4 wv = ((const float4*)w)[tid];
    float4 bv = ((const float4*)bb)[tid];
    bf16x4 o4;
    o4[0] = (bf16_t)((v.x - mean) * rstd * wv.x + bv.x);
    o4[1] = (bf16_t)((v.y - mean) * rstd * wv.y + bv.y);
    o4[2] = (bf16_t)((v.z - mean) * rstd * wv.z + bv.z);
    o4[3] = (bf16_t)((v.w - mean) * rstd * wv.w + bv.w);
    *(bf16x4*)&out[(size_t)row * kC + tid * 4] = o4;
}

// ---------------- generic batched GEMM: C[M,N] = A[M,K] @ W[K,N] (+epilogue) ----------------
// B operand given as WT [N,K] row-major (ldb = row stride of WT).
// EPI: 0 = bf16 out (+bias), 1 = f32 out (+bias +res), 2 = bf16 gelu(+bias), 3 = f32 out * scale
template <int EPI, bool AF32>
__global__ __launch_bounds__(256) void gemm64(const void* __restrict__ Ap, const bf16_t* __restrict__ Bw,
                                              const float* __restrict__ bias, const float* __restrict__ res,
                                              void* __restrict__ Outp, int M, int N, int K, int lda, int ldb,
                                              int ldc, int ldr, long aOuter, long aInner, long bOuter, long bInner,
                                              long oOuter, long oInner, long rOuter, long rInner, int zdiv,
                                              float scale) {
    const int tid = threadIdx.x;
    const int z = blockIdx.z, zo = z / zdiv, zi = z % zdiv;
    const int m0 = blockIdx.y * 64, n0 = blockIdx.x * 64;

    __shared__ __align__(16) bf16_t As[64][72];
    __shared__ __align__(16) bf16_t Bs[64][72];

    const bf16_t* Bz = Bw + zo * bOuter + zi * bInner;
    const bf16_t* Ab = nullptr;
    const float* Af = nullptr;
    if (AF32) Af = (const float*)Ap + zo * aOuter + zi * aInner;
    else      Ab = (const bf16_t*)Ap + zo * aOuter + zi * aInner;

    f32x4 acc[2][2] = {};
    const int srow = tid >> 2;
    const int scol = (tid & 3) * 16;
    const int lane = tid & 63, wid = tid >> 6;
    const int l16 = lane & 15, quad = lane >> 4;
    const int mb = (wid >> 1) * 32, nb = (wid & 1) * 32;

    for (int k0 = 0; k0 < K; k0 += 64) {
        __syncthreads();
        if (AF32) {
            const float* src = Af + (size_t)(m0 + srow) * lda + k0 + scol;
            float4 f0 = ((const float4*)src)[0];
            float4 f1 = ((const float4*)src)[1];
            float4 f2 = ((const float4*)src)[2];
            float4 f3 = ((const float4*)src)[3];
            bf16x8 t0, t1;
            t0[0] = (bf16_t)f0.x; t0[1] = (bf16_t)f0.y; t0[2] = (bf16_t)f0.z; t0[3] = (bf16_t)f0.w;
            t0[4] = (bf16_t)f1.x; t0[5] = (bf16_t)f1.y; t0[6] = (bf16_t)f1.z; t0[7] = (bf16_t)f1.w;
            t1[0] = (bf16_t)f2.x; t1[1] = (bf16_t)f2.y; t1[2] = (bf16_t)f2.z; t1[3] = (bf16_t)f2.w;
            t1[4] = (bf16_t)f3.x; t1[5] = (bf16_t)f3.y; t1[6] = (bf16_t)f3.z; t1[7] = (bf16_t)f3.w;
            *(bf16x8*)&As[srow][scol] = t0;
            *(bf16x8*)&As[srow][scol + 8] = t1;
        } else {
            const uint4* src = (const uint4*)(Ab + (size_t)(m0 + srow) * lda + k0 + scol);
            *(uint4*)&As[srow][scol] = src[0];
            *(uint4*)&As[srow][scol + 8] = src[1];
        }
        {
            const uint4* src = (const uint4*)(Bz + (size_t)(n0 + srow) * ldb + k0 + scol);
            *(uint4*)&Bs[srow][scol] = src[0];
            *(uint4*)&Bs[srow][scol + 8] = src[1];
        }
        __syncthreads();
#pragma unroll
        for (int kk = 0; kk < 64; kk += 32) {
            bf16x8 a0 = *(const bf16x8*)&As[mb + l16][kk + quad * 8];
            bf16x8 a1 = *(const bf16x8*)&As[mb + 16 + l16][kk + quad * 8];
            bf16x8 b0 = *(const bf16x8*)&Bs[nb + l16][kk + quad * 8];
            bf16x8 b1 = *(const bf16x8*)&Bs[nb + 16 + l16][kk + quad * 8];
            acc[0][0] = MFMA16(a0, b0, acc[0][0]);
            acc[0][1] = MFMA16(a0, b1, acc[0][1]);
            acc[1][0] = MFMA16(a1, b0, acc[1][0]);
            acc[1][1] = MFMA16(a1, b1, acc[1][1]);
        }
    }

    const size_t obase = (size_t)(zo * oOuter + zi * oInner);
    const size_t rbase = (size_t)(zo * rOuter + zi * rInner);
#pragma unroll
    for (int mt = 0; mt < 2; ++mt)
#pragma unroll
        for (int nt = 0; nt < 2; ++nt) {
            int n = n0 + nb + nt * 16 + l16;
            float bv = 0.f;
            if constexpr (EPI != 3) { if (bias) bv = bias[n]; }
#pragma unroll
            for (int r = 0; r < 4; ++r) {
                int m = m0 + mb + mt * 16 + quad * 4 + r;
                float v = acc[mt][nt][r] + bv;
                if constexpr (EPI == 2) v = gelu_tanh(v);
                if constexpr (EPI == 3) v *= scale;
                if constexpr (EPI == 1) v += res[rbase + (size_t)m * ldr + n];
                if constexpr (EPI == 0 || EPI == 2) {
                    ((bf16_t*)Outp)[obase + (size_t)m * ldc + n] = (bf16_t)v;
                } else {
                    ((float*)Outp)[obase + (size_t)m * ldc + n] = v;
                }
            }
        }
}

// ---------------- flash causal self-attention ----------------
// qkv: [B*T, 3C] bf16 (Q at col 0, K at col C, V at col 2C; head h occupies cols h*D..h*D+63)
// sa:  [B*T, C] bf16 output
__global__ __launch_bounds__(256) void flash_self(const bf16_t* __restrict__ qkv, bf16_t* __restrict__ sa) {
    const int tid = threadIdx.x;
    const int qt = blockIdx.x, h = blockIdx.y, b = blockIdx.z;
    const int lane = tid & 63, wid = tid >> 6;
    const int l16 = lane & 15, quad = lane >> 4;

    __shared__ __align__(16) bf16_t Qs[64][72];
    __shared__ __align__(16) bf16_t Ks[32][72];
    __shared__ __align__(16) bf16_t VTs[64][40];
    __shared__ __align__(16) bf16_t Ps[4][16][40];

#pragma unroll
    for (int i = 0; i < 2; ++i) {
        int idx = tid + i * 256;
        int row = idx >> 3, col = (idx & 7) * 8;
        const uint4* src = (const uint4*)(qkv + ((size_t)(b * kT + qt * 64 + row)) * (3 * kC) + h * kD + col);
        *(uint4*)&Qs[row][col] = *src;
    }

    float m_prev[4], l_sum[4];
    f32x4 o[4] = {};
#pragma unroll
    for (int r = 0; r < 4; ++r) { m_prev[r] = -1e30f; l_sum[r] = 0.f; }

    const int ktiles = qt * 2 + 2;
    const int qbase = qt * 64 + wid * 16;

    for (int kt = 0; kt < ktiles; ++kt) {
        __syncthreads();
        {
            int row = tid >> 3, col = (tid & 7) * 8;
            size_t gr = ((size_t)(b * kT + kt * 32 + row)) * (3 * kC) + h * kD + col;
            *(uint4*)&Ks[row][col] = *(const uint4*)(qkv + gr + kC);
            uint4 vv = *(const uint4*)(qkv + gr + 2 * kC);
            const unsigned short* vs = (const unsigned short*)&vv;
#pragma unroll
            for (int j = 0; j < 8; ++j)
                *(unsigned short*)&VTs[col + j][row] = vs[j];
        }
        __syncthreads();

        f32x4 sfr[2];
#pragma unroll
        for (int nt = 0; nt < 2; ++nt) {
            f32x4 acc = {};
#pragma unroll
            for (int kk = 0; kk < 64; kk += 32) {
                bf16x8 a = *(const bf16x8*)&Qs[wid * 16 + l16][kk + quad * 8];
                bf16x8 bb = *(const bf16x8*)&Ks[nt * 16 + l16][kk + quad * 8];
                acc = MFMA16(a, bb, acc);
            }
            sfr[nt] = acc;
        }
#pragma unroll
        for (int r = 0; r < 4; ++r) {
            int q = qbase + quad * 4 + r;
            float s0 = sfr[0][r] * kScale, s1 = sfr[1][r] * kScale;
            int k0g = kt * 32 + l16, k1g = k0g + 16;
            if (k0g > q) s0 = -1e30f;
            if (k1g > q) s1 = -1e30f;
            float tm = fmaxf(s0, s1);
#pragma unroll
            for (int off = 1; off < 16; off <<= 1) tm = fmaxf(tm, __shfl_xor(tm, off, 16));
            float mnew = fmaxf(m_prev[r], tm);
            float alpha = __expf(m_prev[r] - mnew);
            float p0 = __expf(s0 - mnew), p1 = __expf(s1 - mnew);
            float ps = p0 + p1;
#pragma unroll
            for (int off = 1; off < 16; off <<= 1) ps += __shfl_xor(ps, off, 16);
            l_sum[r] = l_sum[r] * alpha + ps;
            m_prev[r] = mnew;
#pragma unroll
            for (int t = 0; t < 4; ++t) o[t][r] *= alpha;
            Ps[wid][quad * 4 + r][l16] = (bf16_t)p0;
            Ps[wid][quad * 4 + r][16 + l16] = (bf16_t)p1;
        }
#pragma unroll
        for (int t = 0; t < 4; ++t) {
            bf16x8 a = *(const bf16x8*)&Ps[wid][l16][quad * 8];
            bf16x8 bb = *(const bf16x8*)&VTs[t * 16 + l16][quad * 8];
            o[t] = MFMA16(a, bb, o[t]);
        }
    }

#pragma unroll
    for (int r = 0; r < 4; ++r) {
        float inv = 1.f / l_sum[r];
        size_t row = (size_t)b * kT + qbase + quad * 4 + r;
#pragma unroll
        for (int t = 0; t < 4; ++t)
            sa[row * kC + h * kD + t * 16 + l16] = (bf16_t)(o[t][r] * inv);
    }
}

// ---------------- v2 [B,S,C] -> v2T [B,H,D,S] ----------------
__global__ void v_transpose(const bf16_t* __restrict__ v2, bf16_t* __restrict__ v2T) {
    int idx = blockIdx.x * 256 + threadIdx.x; // over B*H*D*S
    int s = idx % kS;
    int t = idx / kS;
    int d = t % kD; t /= kD;
    int h = t % kH;
    int b = t / kH;
    v2T[idx] = v2[((size_t)(b * kS + s)) * kC + h * kD + d];
}

// ---------------- in-place softmax over rows of 576 fp32 ----------------
__global__ __launch_bounds__(256) void softmax_576(float* __restrict__ p) {
    size_t row = blockIdx.x;
    float* pr = p + row * kS;
    int tid = threadIdx.x;
    float v0 = pr[tid], v1 = pr[tid + 256];
    float v2 = (tid < kS - 512) ? pr[tid + 512] : -1e30f;
    float mx = fmaxf(fmaxf(v0, v1), v2);
#pragma unroll
    for (int o = 32; o > 0; o >>= 1) mx = fmaxf(mx, __shfl_xor(mx, o));
    __shared__ float red[4];
    __shared__ float stat[2];
    int wid = tid >> 6, lane = tid & 63;
    if (lane == 0) red[wid] = mx;
    __syncthreads();
    if (tid == 0) stat[0] = fmaxf(fmaxf(red[0], red[1]), fmaxf(red[2], red[3]));
    __syncthreads();
    mx = stat[0];
    float e0 = __expf(v0 - mx), e1 = __expf(v1 - mx);
    float e2 = (tid < kS - 512) ? __expf(v2 - mx) : 0.f;
    float sum = e0 + e1 + e2;
#pragma unroll
    for (int o = 32; o > 0; o >>= 1) sum += __shfl_xor(sum, o);
    if (lane == 0) red[wid] = sum;
    __syncthreads();
    if (tid == 0) stat[1] = red[0] + red[1] + red[2] + red[3];
    __syncthreads();
    float inv = 1.f / stat[1];
    pr[tid] = e0 * inv;
    pr[tid + 256] = e1 * inv;
    if (tid < kS - 512) pr[tid + 512] = e2 * inv;
}

extern "C" void kernel_launch(void* const* d_in, const int* in_sizes, int n_in, void* d_out, int out_size,
                              void* d_ws, size_t ws_size, hipStream_t stream) {
    const float* x = (const float*)d_in[0];
    const float* context = (const float*)d_in[1];
    const float* ln1_w = (const float*)d_in[2];
    const float* ln1_b = (const float*)d_in[3];
    const float* ln2_w = (const float*)d_in[4];
    const float* ln2_b = (const float*)d_in[5];
    const float* ln3_w = (const float*)d_in[6];
    const float* ln3_b = (const float*)d_in[7];
    const float* attn_wqkv = (const float*)d_in[8];
    const float* attn_bqkv = (const float*)d_in[9];
    const float* attn_wproj = (const float*)d_in[10];
    const float* attn_bproj = (const float*)d_in[11];
    const float* ca_wq = (const float*)d_in[12];
    const float* ca_bq = (const float*)d_in[13];
    const float* ca_wk = (const float*)d_in[14];
    const float* ca_bk = (const float*)d_in[15];
    const float* ca_wv = (const float*)d_in[16];
    const float* ca_bv = (const float*)d_in[17];
    const float* ca_wproj = (const float*)d_in[18];
    const float* ca_bproj = (const float*)d_in[19];
    const float* fc_w = (const float*)d_in[20];
    const float* fc_b = (const float*)d_in[21];
    const float* proj_w = (const float*)d_in[22];
    const float* proj_b = (const float*)d_in[23];

    float* out_x = (float*)d_out;
    float* probs = out_x + (size_t)kB * kT * kC;

    char* wsp = (char*)d_ws;
    size_t off = 0;
    auto alloc = [&](size_t bytes) -> void* {
        void* p = wsp + off;
        off += (bytes + 255) & ~(size_t)255;
        return p;
    };
    bf16_t* wT_qkv   = (bf16_t*)alloc((size_t)3 * kC * kC * 2);
    bf16_t* wT_aproj = (bf16_t*)alloc((size_t)kC * kC * 2);
    bf16_t* wT_caq   = (bf16_t*)alloc((size_t)kC * kC * 2);
    bf16_t* wT_cak   = (bf16_t*)alloc((size_t)kC * kC * 2);
    bf16_t* wT_cav   = (bf16_t*)alloc((size_t)kC * kC * 2);
    bf16_t* wT_caproj= (bf16_t*)alloc((size_t)kC * kC * 2);
    bf16_t* wT_fc    = (bf16_t*)alloc((size_t)4 * kC * kC * 2);
    bf16_t* wT_proj  = (bf16_t*)alloc((size_t)4 * kC * kC * 2);
    bf16_t* hbuf     = (bf16_t*)alloc((size_t)kB * kT * kC * 2);
    bf16_t* qkvb     = (bf16_t*)alloc((size_t)kB * kT * 3 * kC * 2);
    bf16_t* sabuf    = (bf16_t*)alloc((size_t)kB * kT * kC * 2);
    float*  x1       = (float*)alloc((size_t)kB * kT * kC * 4);
    float*  x2       = (float*)alloc((size_t)kB * kT * kC * 4);
    bf16_t* ctxb     = (bf16_t*)alloc((size_t)kB * kS * kC * 2);
    bf16_t* q2       = (bf16_t*)alloc((size_t)kB * kT * kC * 2);
    bf16_t* k2       = (bf16_t*)alloc((size_t)kB * kS * kC * 2);
    bf16_t* v2       = (bf16_t*)alloc((size_t)kB * kS * kC * 2);
    bf16_t* v2T      = (bf16_t*)alloc((size_t)kB * kS * kC * 2);
    bf16_t* hf       = (bf16_t*)alloc((size_t)kB * kT * 4 * kC * 2);
    (void)ws_size;

    dim3 tb(32, 8);
    // weight transposes: transpose_w(W, WT, K, N), grid (N/32, K/32)
    transpose_w<<<dim3(96, 32), tb, 0, stream>>>(attn_wqkv, wT_qkv, kC, 3 * kC);
    transpose_w<<<dim3(32, 32), tb, 0, stream>>>(attn_wproj, wT_aproj, kC, kC);
    transpose_w<<<dim3(32, 32), tb, 0, stream>>>(ca_wq, wT_caq, kC, kC);
    transpose_w<<<dim3(32, 32), tb, 0, stream>>>(ca_wk, wT_cak, kC, kC);
    transpose_w<<<dim3(32, 32), tb, 0, stream>>>(ca_wv, wT_cav, kC, kC);
    transpose_w<<<dim3(32, 32), tb, 0, stream>>>(ca_wproj, wT_caproj, kC, kC);
    transpose_w<<<dim3(128, 32), tb, 0, stream>>>(fc_w, wT_fc, kC, 4 * kC);
    transpose_w<<<dim3(32, 128), tb, 0, stream>>>(proj_w, wT_proj, 4 * kC, kC);
    // context -> bf16
    f32_to_bf16<<<dim3((kB * kS * kC / 4 + 255) / 256), 256, 0, stream>>>(context, ctxb, kB * kS * kC / 4);

    const int Mtok = kB * kT;   // 4096
    const int Mctx = kB * kS;   // 1152

    // LN1
    ln_kernel<<<Mtok, 256, 0, stream>>>(x, ln1_w, ln1_b, hbuf);
    // qkv = h @ Wqkv + b
    gemm64<0, false><<<dim3(48, 64, 1), 256, 0, stream>>>(hbuf, wT_qkv, attn_bqkv, nullptr, qkvb, Mtok, 3 * kC, kC,
                                                          kC, kC, 3 * kC, 0, 0, 0, 0, 0, 0, 0, 0, 0, 1, 1.f);
    // flash self-attn
    flash_self<<<dim3(kT / 64, kH, kB), 256, 0, stream>>>(qkvb, sabuf);
    // x1 = x + sa @ Wproj + b
    gemm64<1, false><<<dim3(16, 64, 1), 256, 0, stream>>>(sabuf, wT_aproj, attn_bproj, x, x1, Mtok, kC, kC, kC, kC,
                                                          kC, kC, 0, 0, 0, 0, 0, 0, 0, 0, 1, 1.f);
    // LN2
    ln_kernel<<<Mtok, 256, 0, stream>>>(x1, ln2_w, ln2_b, hbuf);
    // q2 = h @ Wq + b
    gemm64<0, false><<<dim3(16, 64, 1), 256, 0, stream>>>(hbuf, wT_caq, ca_bq, nullptr, q2, Mtok, kC, kC, kC, kC,
                                                          kC, 0, 0, 0, 0, 0, 0, 0, 0, 0, 1, 1.f);
    // k2 / v2 from context
    gemm64<0, false><<<dim3(16, 18, 1), 256, 0, stream>>>(ctxb, wT_cak, ca_bk, nullptr, k2, Mctx, kC, kC, kC, kC,
                                                          kC, 0, 0, 0, 0, 0, 0, 0, 0, 0, 1, 1.f);
    gemm64<0, false><<<dim3(16, 18, 1), 256, 0, stream>>>(ctxb, wT_cav, ca_bv, nullptr, v2, Mctx, kC, kC, kC, kC,
                                                          kC, 0, 0, 0, 0, 0, 0, 0, 0, 0, 1, 1.f);
    // v2T [B,H,D,S]
    v_transpose<<<dim3(kB * kH * kD * kS / 256), 256, 0, stream>>>(v2, v2T);
    // scores = scale * q2 @ k2^T  -> probs region of d_out (fp32), batched over z = b*H + h
    gemm64<3, false><<<dim3(kS / 64, kT / 64, kB * kH), 256, 0, stream>>>(
        q2, k2, nullptr, nullptr, probs, kT, kS, kD, kC, kC, kS, 0,
        (long)kT * kC, (long)kD, (long)kS * kC, (long)kD,
        (long)kH * kT * kS, (long)kT * kS, 0, 0, kH, kScale);
    // softmax in place
    softmax_576<<<dim3(kB * kH * kT), 256, 0, stream>>>(probs);
    // ca = probs @ v2 -> sabuf (bf16), batched
    gemm64<0, true><<<dim3(1, kT / 64, kB * kH), 256, 0, stream>>>(
        probs, v2T, nullptr, nullptr, sabuf, kT, kD, kS, kS, kS, kC, 0,
        (long)kH * kT * kS, (long)kT * kS, (long)kH * kD * kS, (long)kD * kS,
        (long)kT * kC, (long)kD, 0, 0, kH, 1.f);
    // x2 = x1 + ca @ Wcaproj + b
    gemm64<1, false><<<dim3(16, 64, 1), 256, 0, stream>>>(sabuf, wT_caproj, ca_bproj, x1, x2, Mtok, kC, kC, kC, kC,
                                                          kC, kC, 0, 0, 0, 0, 0, 0, 0, 0, 1, 1.f);
    // LN3
    ln_kernel<<<Mtok, 256, 0, stream>>>(x2, ln3_w, ln3_b, hbuf);
    // hf = gelu(h @ fc_w + b)
    gemm64<2, false><<<dim3(64, 64, 1), 256, 0, stream>>>(hbuf, wT_fc, fc_b, nullptr, hf, Mtok, 4 * kC, kC, kC, kC,
                                                          4 * kC, 0, 0, 0, 0, 0, 0, 0, 0, 0, 1, 1.f);
    // out = x2 + hf @ proj_w + b
    gemm64<1, false><<<dim3(16, 64, 1), 256, 0, stream>>>(hf, wT_proj, proj_b, x2, out_x, Mtok, kC, 4 * kC, 4 * kC,
                                                          4 * kC, kC, kC, 0, 0, 0, 0, 0, 0, 0, 0, 1, 1.f);
}

// Round 2
// 823.904 us; speedup vs baseline: 1.1965x; 1.1965x over previous
//
#include <hip/hip_runtime.h>

typedef __bf16 bf16_t;
typedef __attribute__((ext_vector_type(8))) __bf16 bf16x8;
typedef __attribute__((ext_vector_type(4))) __bf16 bf16x4;
typedef __attribute__((ext_vector_type(4))) float f32x4;

static constexpr int kB = 2, kT = 2048, kS = 576, kC = 1024, kH = 16, kD = 64;
static constexpr float kScale = 0.125f; // 1/sqrt(64)

#define MFMA16(a, b, c) __builtin_amdgcn_mfma_f32_16x16x32_bf16((a), (b), (c), 0, 0, 0)

__device__ __forceinline__ void gld_lds16(const bf16_t* g, bf16_t* l) {
    __builtin_amdgcn_global_load_lds((const __attribute__((address_space(1))) unsigned int*)g,
                                     (__attribute__((address_space(3))) unsigned int*)l, 16, 0, 0);
}

__device__ inline float gelu_tanh(float x) {
    float u = 1.5957691216057308f * (x + 0.044715f * x * x * x); // 2*0.79788456*(...)
    float t = 1.f - 2.f / (__expf(u) + 1.f);                     // tanh(u/... ) via exp(2u)
    return 0.5f * x * (1.f + t);
}

// ---------------- weight transpose + f32->bf16: W[K,N] -> WT[N,K] ----------------
__global__ void transpose_w(const float* __restrict__ W, bf16_t* __restrict__ WT, int K, int N) {
    __shared__ float tile[32][33];
    int n0 = blockIdx.x * 32, k0 = blockIdx.y * 32;
    int tx = threadIdx.x, ty = threadIdx.y;
#pragma unroll
    for (int i = 0; i < 4; ++i)
        tile[ty + i * 8][tx] = W[(size_t)(k0 + ty + i * 8) * N + n0 + tx];
    __syncthreads();
#pragma unroll
    for (int i = 0; i < 4; ++i)
        WT[(size_t)(n0 + ty + i * 8) * K + k0 + tx] = (bf16_t)tile[tx][ty + i * 8];
}

// ---------------- f32 -> bf16 elementwise (n4 = count/4) ----------------
__global__ void f32_to_bf16(const float* __restrict__ in, bf16_t* __restrict__ out, int n4) {
    int i = blockIdx.x * 256 + threadIdx.x;
    if (i < n4) {
        float4 v = ((const float4*)in)[i];
        bf16x4 o;
        o[0] = (bf16_t)v.x; o[1] = (bf16_t)v.y; o[2] = (bf16_t)v.z; o[3] = (bf16_t)v.w;
        ((bf16x4*)out)[i] = o;
    }
}

// ---------------- LayerNorm: fp32 in [rows, 1024] -> bf16 out ----------------
__global__ __launch_bounds__(256) void ln_kernel(const float* __restrict__ x,
                                                 const float* __restrict__ w,
                                                 const float* __restrict__ bb,
                                                 bf16_t* __restrict__ out) {
    int row = blockIdx.x, tid = threadIdx.x;
    const float* xr = x + (size_t)row * kC;
    float4 v = ((const float4*)xr)[tid];
    float s1 = v.x + v.y + v.z + v.w;
    float s2 = v.x * v.x + v.y * v.y + v.z * v.z + v.w * v.w;
#pragma unroll
    for (int o = 32; o > 0; o >>= 1) {
        s1 += __shfl_down(s1, o);
        s2 += __shfl_down(s2, o);
    }
    __shared__ float red[8];
    __shared__ float mv[2];
    int wid = tid >> 6, lane = tid & 63;
    if (lane == 0) { red[wid] = s1; red[4 + wid] = s2; }
    __syncthreads();
    if (tid == 0) {
        float a = red[0] + red[1] + red[2] + red[3];
        float c = red[4] + red[5] + red[6] + red[7];
        float mean = a * (1.f / kC);
        float var = c * (1.f / kC) - mean * mean;
        mv[0] = mean;
        mv[1] = rsqrtf(var + 1e-5f);
    }
    __syncthreads();
    float mean = mv[0], rstd = mv[1];
    float4 wv = ((const float4*)w)[tid];
    float4 bv = ((const float4*)bb)[tid];
    bf16x4 o4;
    o4[0] = (bf16_t)((v.x - mean) * rstd * wv.x + bv.x);
    o4[1] = (bf16_t)((v.y - mean) * rstd * wv.y + bv.y);
    o4[2] = (bf16_t)((v.z - mean) * rstd * wv.z + bv.z);
    o4[3] = (bf16_t)((v.w - mean) * rstd * wv.w + bv.w);
    *(bf16x4*)&out[(size_t)row * kC + tid * 4] = o4;
}

// ---------------- m97-style GEMM: C[M,N] = A[M,K] @ WT[N,K]^T (+epilogue) ----------------
// BM in {64,128}, BN=128, BK=64. global_load_lds staging, unpadded LDS.
// EPI: 0 bf16+bias, 1 f32 = acc+bias+res, 2 bf16 gelu(acc+bias), 4 qkv-split (Out=q,Out2=k,Out3=vT)
template <int EPI, int BM>
__global__ __launch_bounds__(256) void gemm128(const bf16_t* __restrict__ A, const bf16_t* __restrict__ Bw,
                                               const float* __restrict__ bias, const float* __restrict__ res,
                                               void* __restrict__ Out, void* __restrict__ Out2,
                                               void* __restrict__ Out3, int M, int N, int K, int lda, int ldb,
                                               int ldc) {
    constexpr int MT = BM / 32;       // m-tiles of 16 per wave
    __shared__ __align__(16) bf16_t As[BM * 64];
    __shared__ __align__(16) bf16_t Bs[128 * 64];
    const int tid = threadIdx.x;
    const int m0 = blockIdx.y * BM, n0 = blockIdx.x * 128;
    const int lane = tid & 63, wid = tid >> 6;
    const int l16 = lane & 15, quad = lane >> 4;
    const int wm = (wid >> 1) * (BM / 2), wn = (wid & 1) * 64;
    f32x4 acc[MT][4] = {};

    const bf16_t* Ab = A + (size_t)m0 * lda;
    const bf16_t* Bb = Bw + (size_t)n0 * ldb;

    for (int k0 = 0; k0 < K; k0 += 64) {
        __syncthreads();
#pragma unroll
        for (int i = 0; i < BM / 32; ++i) {
            int chunk = tid + i * 256;
            int row = chunk >> 3, col = (chunk & 7) * 8;
            gld_lds16(Ab + (size_t)row * lda + k0 + col, As + row * 64 + col);
        }
#pragma unroll
        for (int i = 0; i < 4; ++i) {
            int chunk = tid + i * 256;
            int row = chunk >> 3, col = (chunk & 7) * 8;
            gld_lds16(Bb + (size_t)row * ldb + k0 + col, Bs + row * 64 + col);
        }
        __syncthreads();
#pragma unroll
        for (int kk = 0; kk < 64; kk += 32) {
            bf16x8 af[MT], bw[4];
#pragma unroll
            for (int mt = 0; mt < MT; ++mt)
                af[mt] = *(const bf16x8*)&As[(wm + mt * 16 + l16) * 64 + kk + quad * 8];
#pragma unroll
            for (int nt = 0; nt < 4; ++nt)
                bw[nt] = *(const bf16x8*)&Bs[(wn + nt * 16 + l16) * 64 + kk + quad * 8];
#pragma unroll
            for (int mt = 0; mt < MT; ++mt)
#pragma unroll
                for (int nt = 0; nt < 4; ++nt) acc[mt][nt] = MFMA16(af[mt], bw[nt], acc[mt][nt]);
        }
    }

#pragma unroll
    for (int mt = 0; mt < MT; ++mt)
#pragma unroll
        for (int nt = 0; nt < 4; ++nt) {
            int n = n0 + wn + nt * 16 + l16;
            float bv = bias ? bias[n] : 0.f;
#pragma unroll
            for (int r = 0; r < 4; ++r) {
                int m = m0 + wm + mt * 16 + quad * 4 + r;
                float v = acc[mt][nt][r] + bv;
                if constexpr (EPI == 2) v = gelu_tanh(v);
                if constexpr (EPI == 0 || EPI == 2) {
                    ((bf16_t*)Out)[(size_t)m * ldc + n] = (bf16_t)v;
                } else if constexpr (EPI == 1) {
                    ((float*)Out)[(size_t)m * ldc + n] = v + res[(size_t)m * ldc + n];
                } else { // EPI 4: qkv split. m -> (b,t); n -> which/h/d
                    int b = m >> 11, t = m & 2047;
                    if (n < 2048) {
                        int h = (n & 1023) >> 6, d = n & 63;
                        bf16_t* dst = (n < 1024) ? (bf16_t*)Out : (bf16_t*)Out2;
                        dst[(((size_t)b * kH + h) * kT + t) * kD + d] = (bf16_t)v;
                    } else {
                        int n2 = n - 2048;
                        int h = n2 >> 6, d = n2 & 63;
                        ((bf16_t*)Out3)[(((size_t)b * kH + h) * kD + d) * kT + t] = (bf16_t)v;
                    }
                }
            }
        }
}

// ---------------- legacy 64x64 GEMM (small/batched shapes) ----------------
// EPI: 0 = bf16 out (+bias)
template <int EPI, bool AF32>
__global__ __launch_bounds__(256) void gemm64(const void* __restrict__ Ap, const bf16_t* __restrict__ Bw,
                                              const float* __restrict__ bias, const float* __restrict__ res,
                                              void* __restrict__ Outp, int M, int N, int K, int lda, int ldb,
                                              int ldc, int ldr, long aOuter, long aInner, long bOuter, long bInner,
                                              long oOuter, long oInner, long rOuter, long rInner, int zdiv,
                                              float scale) {
    const int tid = threadIdx.x;
    const int z = blockIdx.z, zo = z / zdiv, zi = z % zdiv;
    const int m0 = blockIdx.y * 64, n0 = blockIdx.x * 64;

    __shared__ __align__(16) bf16_t As[64][72];
    __shared__ __align__(16) bf16_t Bs[64][72];

    const bf16_t* Bz = Bw + zo * bOuter + zi * bInner;
    const bf16_t* Ab = nullptr;
    const float* Af = nullptr;
    if (AF32) Af = (const float*)Ap + zo * aOuter + zi * aInner;
    else      Ab = (const bf16_t*)Ap + zo * aOuter + zi * aInner;

    f32x4 acc[2][2] = {};
    const int srow = tid >> 2;
    const int scol = (tid & 3) * 16;
    const int lane = tid & 63, wid = tid >> 6;
    const int l16 = lane & 15, quad = lane >> 4;
    const int mb = (wid >> 1) * 32, nb = (wid & 1) * 32;

    for (int k0 = 0; k0 < K; k0 += 64) {
        __syncthreads();
        if (AF32) {
            const float* src = Af + (size_t)(m0 + srow) * lda + k0 + scol;
            float4 f0 = ((const float4*)src)[0];
            float4 f1 = ((const float4*)src)[1];
            float4 f2 = ((const float4*)src)[2];
            float4 f3 = ((const float4*)src)[3];
            bf16x8 t0, t1;
            t0[0] = (bf16_t)f0.x; t0[1] = (bf16_t)f0.y; t0[2] = (bf16_t)f0.z; t0[3] = (bf16_t)f0.w;
            t0[4] = (bf16_t)f1.x; t0[5] = (bf16_t)f1.y; t0[6] = (bf16_t)f1.z; t0[7] = (bf16_t)f1.w;
            t1[0] = (bf16_t)f2.x; t1[1] = (bf16_t)f2.y; t1[2] = (bf16_t)f2.z; t1[3] = (bf16_t)f2.w;
            t1[4] = (bf16_t)f3.x; t1[5] = (bf16_t)f3.y; t1[6] = (bf16_t)f3.z; t1[7] = (bf16_t)f3.w;
            *(bf16x8*)&As[srow][scol] = t0;
            *(bf16x8*)&As[srow][scol + 8] = t1;
        } else {
            const uint4* src = (const uint4*)(Ab + (size_t)(m0 + srow) * lda + k0 + scol);
            *(uint4*)&As[srow][scol] = src[0];
            *(uint4*)&As[srow][scol + 8] = src[1];
        }
        {
            const uint4* src = (const uint4*)(Bz + (size_t)(n0 + srow) * ldb + k0 + scol);
            *(uint4*)&Bs[srow][scol] = src[0];
            *(uint4*)&Bs[srow][scol + 8] = src[1];
        }
        __syncthreads();
#pragma unroll
        for (int kk = 0; kk < 64; kk += 32) {
            bf16x8 a0 = *(const bf16x8*)&As[mb + l16][kk + quad * 8];
            bf16x8 a1 = *(const bf16x8*)&As[mb + 16 + l16][kk + quad * 8];
            bf16x8 b0 = *(const bf16x8*)&Bs[nb + l16][kk + quad * 8];
            bf16x8 b1 = *(const bf16x8*)&Bs[nb + 16 + l16][kk + quad * 8];
            acc[0][0] = MFMA16(a0, b0, acc[0][0]);
            acc[0][1] = MFMA16(a0, b1, acc[0][1]);
            acc[1][0] = MFMA16(a1, b0, acc[1][0]);
            acc[1][1] = MFMA16(a1, b1, acc[1][1]);
        }
    }

    const size_t obase = (size_t)(zo * oOuter + zi * oInner);
#pragma unroll
    for (int mt = 0; mt < 2; ++mt)
#pragma unroll
        for (int nt = 0; nt < 2; ++nt) {
            int n = n0 + nb + nt * 16 + l16;
            float bv = 0.f;
            if (bias) bv = bias[n];
#pragma unroll
            for (int r = 0; r < 4; ++r) {
                int m = m0 + mb + mt * 16 + quad * 4 + r;
                float v = acc[mt][nt][r] + bv;
                ((bf16_t*)Outp)[obase + (size_t)m * ldc + n] = (bf16_t)v;
            }
        }
    (void)res; (void)ldr; (void)scale;
}

// ---------------- flash causal self-attention v2 ----------------
// q,k: [b,h,t,d] bf16 (q pre-scaled NOT needed; scaled at staging); vT: [b,h,d,t]
__global__ __launch_bounds__(256) void flash_self2(const bf16_t* __restrict__ qb, const bf16_t* __restrict__ kb,
                                                   const bf16_t* __restrict__ vT, bf16_t* __restrict__ sa) {
    const int tid = threadIdx.x;
    const int qi = gridDim.x - 1 - blockIdx.x; // heavy blocks first
    const int h = blockIdx.y, b = blockIdx.z;
    const int lane = tid & 63, wid = tid >> 6;
    const int l16 = lane & 15, quad = lane >> 4;
    const size_t bh = (size_t)b * kH + h;

    __shared__ __align__(16) bf16_t Qs[64][72];
    __shared__ __align__(16) bf16_t Ks[64][72];
    __shared__ __align__(16) bf16_t VTs[64][72];
    __shared__ __align__(16) bf16_t Ps[64][72];

    const int srow = tid >> 2, scol = (tid & 3) * 16;
    {
        const bf16_t* src = qb + (bh * kT + qi * 64 + srow) * kD + scol;
        bf16x8 q0 = ((const bf16x8*)src)[0];
        bf16x8 q1 = ((const bf16x8*)src)[1];
#pragma unroll
        for (int j = 0; j < 8; ++j) { q0[j] = q0[j] * (bf16_t)0.125f; q1[j] = q1[j] * (bf16_t)0.125f; }
        *(bf16x8*)&Qs[srow][scol] = q0;
        *(bf16x8*)&Qs[srow][scol + 8] = q1;
    }

    float m_prev[4], l_sum[4];
    f32x4 o[4] = {};
#pragma unroll
    for (int r = 0; r < 4; ++r) { m_prev[r] = -1e30f; l_sum[r] = 0.f; }

    const int qrow0 = qi * 64 + wid * 16;

    for (int kt = 0; kt <= qi; ++kt) {
        __syncthreads();
        {
            const bf16_t* ks = kb + (bh * kT + kt * 64 + srow) * kD + scol;
            *(uint4*)&Ks[srow][scol] = ((const uint4*)ks)[0];
            *(uint4*)&Ks[srow][scol + 8] = ((const uint4*)ks)[1];
            const bf16_t* vs = vT + (bh * kD + srow) * kT + kt * 64 + scol;
            *(uint4*)&VTs[srow][scol] = ((const uint4*)vs)[0];
            *(uint4*)&VTs[srow][scol + 8] = ((const uint4*)vs)[1];
        }
        __syncthreads();

        f32x4 sf[4];
#pragma unroll
        for (int nt = 0; nt < 4; ++nt) {
            f32x4 a = {};
            sf[nt] = a;
        }
#pragma unroll
        for (int kk = 0; kk < 64; kk += 32) {
            bf16x8 aq = *(const bf16x8*)&Qs[wid * 16 + l16][kk + quad * 8];
#pragma unroll
            for (int nt = 0; nt < 4; ++nt) {
                bf16x8 bk = *(const bf16x8*)&Ks[nt * 16 + l16][kk + quad * 8];
                sf[nt] = MFMA16(aq, bk, sf[nt]);
            }
        }

#pragma unroll
        for (int r = 0; r < 4; ++r) {
            int q = qrow0 + quad * 4 + r;
            float sv[4];
#pragma unroll
            for (int nt = 0; nt < 4; ++nt) sv[nt] = sf[nt][r];
            if (kt == qi) {
#pragma unroll
                for (int nt = 0; nt < 4; ++nt)
                    if (kt * 64 + nt * 16 + l16 > q) sv[nt] = -1e30f;
            }
            float tm = fmaxf(fmaxf(sv[0], sv[1]), fmaxf(sv[2], sv[3]));
#pragma unroll
            for (int off = 1; off < 16; off <<= 1) tm = fmaxf(tm, __shfl_xor(tm, off, 16));
            float mnew = fmaxf(m_prev[r], tm);
            float alpha = __expf(m_prev[r] - mnew);
            float p[4], ps = 0.f;
#pragma unroll
            for (int nt = 0; nt < 4; ++nt) { p[nt] = __expf(sv[nt] - mnew); ps += p[nt]; }
#pragma unroll
            for (int off = 1; off < 16; off <<= 1) ps += __shfl_xor(ps, off, 16);
            l_sum[r] = l_sum[r] * alpha + ps;
            m_prev[r] = mnew;
#pragma unroll
            for (int dt = 0; dt < 4; ++dt) o[dt][r] *= alpha;
#pragma unroll
            for (int nt = 0; nt < 4; ++nt) Ps[wid * 16 + quad * 4 + r][nt * 16 + l16] = (bf16_t)p[nt];
        }

#pragma unroll
        for (int kk = 0; kk < 64; kk += 32) {
            bf16x8 ap = *(const bf16x8*)&Ps[wid * 16 + l16][kk + quad * 8];
#pragma unroll
            for (int dt = 0; dt < 4; ++dt) {
                bf16x8 bv = *(const bf16x8*)&VTs[dt * 16 + l16][kk + quad * 8];
                o[dt] = MFMA16(ap, bv, o[dt]);
            }
        }
    }

#pragma unroll
    for (int r = 0; r < 4; ++r) {
        float inv = 1.f / l_sum[r];
        size_t row = (size_t)b * kT + qi * 64 + wid * 16 + quad * 4 + r;
#pragma unroll
        for (int dt = 0; dt < 4; ++dt)
            sa[row * kC + h * kD + dt * 16 + l16] = (bf16_t)(o[dt][r] * inv);
    }
}

// ---------------- fused cross-attn scores + softmax -> probs fp32 [b,h,t,s] ----------------
__global__ __launch_bounds__(256) void ca_scores(const bf16_t* __restrict__ q2, const bf16_t* __restrict__ k2,
                                                 float* __restrict__ probs) {
    const int tid = threadIdx.x;
    const int qi = blockIdx.x, z = blockIdx.y;
    const int b = z >> 4, h = z & 15;
    const int lane = tid & 63, wid = tid >> 6;
    const int l16 = lane & 15, quad = lane >> 4;

    __shared__ __align__(16) bf16_t Qs[64][72];
    __shared__ __align__(16) bf16_t Ks[64][72];

    const int srow = tid >> 2, scol = (tid & 3) * 16;
    {
        const bf16_t* src = q2 + ((size_t)b * kT + qi * 64 + srow) * kC + h * kD + scol;
        bf16x8 q0 = ((const bf16x8*)src)[0];
        bf16x8 q1 = ((const bf16x8*)src)[1];
#pragma unroll
        for (int j = 0; j < 8; ++j) { q0[j] = q0[j] * (bf16_t)0.125f; q1[j] = q1[j] * (bf16_t)0.125f; }
        *(bf16x8*)&Qs[srow][scol] = q0;
        *(bf16x8*)&Qs[srow][scol + 8] = q1;
    }

    f32x4 S[9][4] = {};
    for (int kt = 0; kt < 9; ++kt) {
        __syncthreads();
        {
            const bf16_t* ks = k2 + ((size_t)b * kS + kt * 64 + srow) * kC + h * kD + scol;
            *(uint4*)&Ks[srow][scol] = ((const uint4*)ks)[0];
            *(uint4*)&Ks[srow][scol + 8] = ((const uint4*)ks)[1];
        }
        __syncthreads();
#pragma unroll
        for (int kk = 0; kk < 64; kk += 32) {
            bf16x8 aq = *(const bf16x8*)&Qs[wid * 16 + l16][kk + quad * 8];
#pragma unroll
            for (int nt = 0; nt < 4; ++nt) {
                bf16x8 bk = *(const bf16x8*)&Ks[nt * 16 + l16][kk + quad * 8];
                S[kt][nt] = MFMA16(aq, bk, S[kt][nt]);
            }
        }
    }

#pragma unroll
    for (int r = 0; r < 4; ++r) {
        float mx = -1e30f;
#pragma unroll
        for (int j = 0; j < 9; ++j)
#pragma unroll
            for (int nt = 0; nt < 4; ++nt) mx = fmaxf(mx, S[j][nt][r]);
#pragma unroll
        for (int off = 1; off < 16; off <<= 1) mx = fmaxf(mx, __shfl_xor(mx, off, 16));
        float sum = 0.f;
        float e[36];
#pragma unroll
        for (int j = 0; j < 9; ++j)
#pragma unroll
            for (int nt = 0; nt < 4; ++nt) {
                float v = __expf(S[j][nt][r] - mx);
                e[j * 4 + nt] = v;
                sum += v;
            }
#pragma unroll
        for (int off = 1; off < 16; off <<= 1) sum += __shfl_xor(sum, off, 16);
        float inv = 1.f / sum;
        int q = qi * 64 + wid * 16 + quad * 4 + r;
        float* dst = probs + ((size_t)z * kT + q) * kS;
#pragma unroll
        for (int j = 0; j < 9; ++j)
#pragma unroll
            for (int nt = 0; nt < 4; ++nt) dst[j * 64 + nt * 16 + l16] = e[j * 4 + nt] * inv;
    }
}

// ---------------- v2 [B,S,C] -> v2T [B,H,D,S] ----------------
__global__ void v_transpose(const bf16_t* __restrict__ v2, bf16_t* __restrict__ v2T) {
    int idx = blockIdx.x * 256 + threadIdx.x; // over B*H*D*S
    int s = idx % kS;
    int t = idx / kS;
    int d = t % kD; t /= kD;
    int h = t % kH;
    int b = t / kH;
    v2T[idx] = v2[((size_t)(b * kS + s)) * kC + h * kD + d];
}

extern "C" void kernel_launch(void* const* d_in, const int* in_sizes, int n_in, void* d_out, int out_size,
                              void* d_ws, size_t ws_size, hipStream_t stream) {
    const float* x = (const float*)d_in[0];
    const float* context = (const float*)d_in[1];
    const float* ln1_w = (const float*)d_in[2];
    const float* ln1_b = (const float*)d_in[3];
    const float* ln2_w = (const float*)d_in[4];
    const float* ln2_b = (const float*)d_in[5];
    const float* ln3_w = (const float*)d_in[6];
    const float* ln3_b = (const float*)d_in[7];
    const float* attn_wqkv = (const float*)d_in[8];
    const float* attn_bqkv = (const float*)d_in[9];
    const float* attn_wproj = (const float*)d_in[10];
    const float* attn_bproj = (const float*)d_in[11];
    const float* ca_wq = (const float*)d_in[12];
    const float* ca_bq = (const float*)d_in[13];
    const float* ca_wk = (const float*)d_in[14];
    const float* ca_bk = (const float*)d_in[15];
    const float* ca_wv = (const float*)d_in[16];
    const float* ca_bv = (const float*)d_in[17];
    const float* ca_wproj = (const float*)d_in[18];
    const float* ca_bproj = (const float*)d_in[19];
    const float* fc_w = (const float*)d_in[20];
    const float* fc_b = (const float*)d_in[21];
    const float* proj_w = (const float*)d_in[22];
    const float* proj_b = (const float*)d_in[23];

    float* out_x = (float*)d_out;
    float* probs = out_x + (size_t)kB * kT * kC;

    char* wsp = (char*)d_ws;
    size_t off = 0;
    auto alloc = [&](size_t bytes) -> void* {
        void* p = wsp + off;
        off += (bytes + 255) & ~(size_t)255;
        return p;
    };
    bf16_t* wT_qkv   = (bf16_t*)alloc((size_t)3 * kC * kC * 2);
    bf16_t* wT_aproj = (bf16_t*)alloc((size_t)kC * kC * 2);
    bf16_t* wT_caq   = (bf16_t*)alloc((size_t)kC * kC * 2);
    bf16_t* wT_cak   = (bf16_t*)alloc((size_t)kC * kC * 2);
    bf16_t* wT_cav   = (bf16_t*)alloc((size_t)kC * kC * 2);
    bf16_t* wT_caproj= (bf16_t*)alloc((size_t)kC * kC * 2);
    bf16_t* wT_fc    = (bf16_t*)alloc((size_t)4 * kC * kC * 2);
    bf16_t* wT_proj  = (bf16_t*)alloc((size_t)4 * kC * kC * 2);
    bf16_t* hbuf     = (bf16_t*)alloc((size_t)kB * kT * kC * 2);
    bf16_t* qb       = (bf16_t*)alloc((size_t)kB * kT * kC * 2);
    bf16_t* kbuf     = (bf16_t*)alloc((size_t)kB * kT * kC * 2);
    bf16_t* vTb      = (bf16_t*)alloc((size_t)kB * kT * kC * 2);
    bf16_t* sabuf    = (bf16_t*)alloc((size_t)kB * kT * kC * 2);
    float*  x1       = (float*)alloc((size_t)kB * kT * kC * 4);
    float*  x2       = (float*)alloc((size_t)kB * kT * kC * 4);
    bf16_t* ctxb     = (bf16_t*)alloc((size_t)kB * kS * kC * 2);
    bf16_t* q2       = (bf16_t*)alloc((size_t)kB * kT * kC * 2);
    bf16_t* k2       = (bf16_t*)alloc((size_t)kB * kS * kC * 2);
    bf16_t* v2       = (bf16_t*)alloc((size_t)kB * kS * kC * 2);
    bf16_t* v2T      = (bf16_t*)alloc((size_t)kB * kS * kC * 2);
    bf16_t* hf       = (bf16_t*)alloc((size_t)kB * kT * 4 * kC * 2);
    (void)ws_size;

    dim3 tb(32, 8);
    transpose_w<<<dim3(96, 32), tb, 0, stream>>>(attn_wqkv, wT_qkv, kC, 3 * kC);
    transpose_w<<<dim3(32, 32), tb, 0, stream>>>(attn_wproj, wT_aproj, kC, kC);
    transpose_w<<<dim3(32, 32), tb, 0, stream>>>(ca_wq, wT_caq, kC, kC);
    transpose_w<<<dim3(32, 32), tb, 0, stream>>>(ca_wk, wT_cak, kC, kC);
    transpose_w<<<dim3(32, 32), tb, 0, stream>>>(ca_wv, wT_cav, kC, kC);
    transpose_w<<<dim3(32, 32), tb, 0, stream>>>(ca_wproj, wT_caproj, kC, kC);
    transpose_w<<<dim3(128, 32), tb, 0, stream>>>(fc_w, wT_fc, kC, 4 * kC);
    transpose_w<<<dim3(32, 128), tb, 0, stream>>>(proj_w, wT_proj, 4 * kC, kC);
    f32_to_bf16<<<dim3((kB * kS * kC / 4 + 255) / 256), 256, 0, stream>>>(context, ctxb, kB * kS * kC / 4);

    const int Mtok = kB * kT;   // 4096
    const int Mctx = kB * kS;   // 1152

    // LN1 -> hbuf
    ln_kernel<<<Mtok, 256, 0, stream>>>(x, ln1_w, ln1_b, hbuf);
    // qkv: split epilogue -> qb [b,h,t,d], kbuf [b,h,t,d], vTb [b,h,d,t]
    gemm128<4, 128><<<dim3(24, 32), 256, 0, stream>>>(hbuf, wT_qkv, attn_bqkv, nullptr, qb, kbuf, vTb, Mtok,
                                                      3 * kC, kC, kC, kC, 0);
    // flash self-attn
    flash_self2<<<dim3(kT / 64, kH, kB), 256, 0, stream>>>(qb, kbuf, vTb, sabuf);
    // x1 = x + sa @ Wproj + b
    gemm128<1, 64><<<dim3(8, 64), 256, 0, stream>>>(sabuf, wT_aproj, attn_bproj, x, x1, nullptr, nullptr, Mtok,
                                                    kC, kC, kC, kC, kC);
    // LN2 -> hbuf
    ln_kernel<<<Mtok, 256, 0, stream>>>(x1, ln2_w, ln2_b, hbuf);
    // q2 = h @ Wq + b
    gemm128<0, 64><<<dim3(8, 64), 256, 0, stream>>>(hbuf, wT_caq, ca_bq, nullptr, q2, nullptr, nullptr, Mtok, kC,
                                                    kC, kC, kC, kC);
    // k2 / v2 from context
    gemm64<0, false><<<dim3(16, 18, 1), 256, 0, stream>>>(ctxb, wT_cak, ca_bk, nullptr, k2, Mctx, kC, kC, kC, kC,
                                                          kC, 0, 0, 0, 0, 0, 0, 0, 0, 0, 1, 1.f);
    gemm64<0, false><<<dim3(16, 18, 1), 256, 0, stream>>>(ctxb, wT_cav, ca_bv, nullptr, v2, Mctx, kC, kC, kC, kC,
                                                          kC, 0, 0, 0, 0, 0, 0, 0, 0, 0, 1, 1.f);
    v_transpose<<<dim3(kB * kH * kD * kS / 256), 256, 0, stream>>>(v2, v2T);
    // fused scores+softmax -> probs (d_out)
    ca_scores<<<dim3(kT / 64, kB * kH), 256, 0, stream>>>(q2, k2, probs);
    // ca = probs @ v2 -> sabuf (bf16), batched
    gemm64<0, true><<<dim3(1, kT / 64, kB * kH), 256, 0, stream>>>(
        probs, v2T, nullptr, nullptr, sabuf, kT, kD, kS, kS, kS, kC, 0,
        (long)kH * kT * kS, (long)kT * kS, (long)kH * kD * kS, (long)kD * kS,
        (long)kT * kC, (long)kD, 0, 0, kH, 1.f);
    // x2 = x1 + ca @ Wcaproj + b
    gemm128<1, 64><<<dim3(8, 64), 256, 0, stream>>>(sabuf, wT_caproj, ca_bproj, x1, x2, nullptr, nullptr, Mtok,
                                                    kC, kC, kC, kC, kC);
    // LN3 -> hbuf
    ln_kernel<<<Mtok, 256, 0, stream>>>(x2, ln3_w, ln3_b, hbuf);
    // hf = gelu(h @ fc_w + b)
    gemm128<2, 128><<<dim3(32, 32), 256, 0, stream>>>(hbuf, wT_fc, fc_b, nullptr, hf, nullptr, nullptr, Mtok,
                                                      4 * kC, kC, kC, kC, 4 * kC);
    // out = x2 + hf @ proj_w + b
    gemm128<1, 64><<<dim3(8, 64), 256, 0, stream>>>(hf, wT_proj, proj_b, x2, out_x, nullptr, nullptr, Mtok, kC,
                                                    4 * kC, 4 * kC, 4 * kC, kC);
}

// Round 3
// 778.061 us; speedup vs baseline: 1.2670x; 1.0589x over previous
//
#include <hip/hip_runtime.h>

typedef __bf16 bf16_t;
typedef __attribute__((ext_vector_type(8))) __bf16 bf16x8;
typedef __attribute__((ext_vector_type(4))) __bf16 bf16x4;
typedef __attribute__((ext_vector_type(4))) float f32x4;

static constexpr int kB = 2, kT = 2048, kS = 576, kC = 1024, kH = 16, kD = 64;

#define MFMA16(a, b, c) __builtin_amdgcn_mfma_f32_16x16x32_bf16((a), (b), (c), 0, 0, 0)

__device__ __forceinline__ void gld_lds16(const bf16_t* g, bf16_t* l) {
    __builtin_amdgcn_global_load_lds((const __attribute__((address_space(1))) unsigned int*)g,
                                     (__attribute__((address_space(3))) unsigned int*)l, 16, 0, 0);
}

__device__ inline float gelu_tanh(float x) {
    float u = 1.5957691216057308f * (x + 0.044715f * x * x * x);
    float t = 1.f - 2.f / (__expf(u) + 1.f);
    return 0.5f * x * (1.f + t);
}

// ---------------- weight transpose + f32->bf16: W[K,N] -> WT[N,K] ----------------
__global__ void transpose_w(const float* __restrict__ W, bf16_t* __restrict__ WT, int K, int N) {
    __shared__ float tile[32][33];
    int n0 = blockIdx.x * 32, k0 = blockIdx.y * 32;
    int tx = threadIdx.x, ty = threadIdx.y;
#pragma unroll
    for (int i = 0; i < 4; ++i)
        tile[ty + i * 8][tx] = W[(size_t)(k0 + ty + i * 8) * N + n0 + tx];
    __syncthreads();
#pragma unroll
    for (int i = 0; i < 4; ++i)
        WT[(size_t)(n0 + ty + i * 8) * K + k0 + tx] = (bf16_t)tile[tx][ty + i * 8];
}

// ---------------- f32 -> bf16 elementwise (n4 = count/4) ----------------
__global__ void f32_to_bf16(const float* __restrict__ in, bf16_t* __restrict__ out, int n4) {
    int i = blockIdx.x * 256 + threadIdx.x;
    if (i < n4) {
        float4 v = ((const float4*)in)[i];
        bf16x4 o;
        o[0] = (bf16_t)v.x; o[1] = (bf16_t)v.y; o[2] = (bf16_t)v.z; o[3] = (bf16_t)v.w;
        ((bf16x4*)out)[i] = o;
    }
}

// ---------------- LayerNorm: fp32 in [rows, 1024] -> bf16 out ----------------
__global__ __launch_bounds__(256) void ln_kernel(const float* __restrict__ x,
                                                 const float* __restrict__ w,
                                                 const float* __restrict__ bb,
                                                 bf16_t* __restrict__ out) {
    int row = blockIdx.x, tid = threadIdx.x;
    const float* xr = x + (size_t)row * kC;
    float4 v = ((const float4*)xr)[tid];
    float s1 = v.x + v.y + v.z + v.w;
    float s2 = v.x * v.x + v.y * v.y + v.z * v.z + v.w * v.w;
#pragma unroll
    for (int o = 32; o > 0; o >>= 1) {
        s1 += __shfl_down(s1, o);
        s2 += __shfl_down(s2, o);
    }
    __shared__ float red[8];
    __shared__ float mv[2];
    int wid = tid >> 6, lane = tid & 63;
    if (lane == 0) { red[wid] = s1; red[4 + wid] = s2; }
    __syncthreads();
    if (tid == 0) {
        float a = red[0] + red[1] + red[2] + red[3];
        float c = red[4] + red[5] + red[6] + red[7];
        float mean = a * (1.f / kC);
        float var = c * (1.f / kC) - mean * mean;
        mv[0] = mean;
        mv[1] = rsqrtf(var + 1e-5f);
    }
    __syncthreads();
    float mean = mv[0], rstd = mv[1];
    float4 wv = ((const float4*)w)[tid];
    float4 bv = ((const float4*)bb)[tid];
    bf16x4 o4;
    o4[0] = (bf16_t)((v.x - mean) * rstd * wv.x + bv.x);
    o4[1] = (bf16_t)((v.y - mean) * rstd * wv.y + bv.y);
    o4[2] = (bf16_t)((v.z - mean) * rstd * wv.z + bv.z);
    o4[3] = (bf16_t)((v.w - mean) * rstd * wv.w + bv.w);
    *(bf16x4*)&out[(size_t)row * kC + tid * 4] = o4;
}

// ---------------- m97-style GEMM: C[M,N] = A[M,K] @ WT[N,K]^T (+epilogue) ----------------
// EPI: 0 bf16+bias, 1 f32 = acc+bias+res, 2 bf16 gelu(acc+bias), 4 qkv-split (Out=q,Out2=k,Out3=vT)
template <int EPI, int BM>
__global__ __launch_bounds__(256) void gemm128(const bf16_t* __restrict__ A, const bf16_t* __restrict__ Bw,
                                               const float* __restrict__ bias, const float* __restrict__ res,
                                               void* __restrict__ Out, void* __restrict__ Out2,
                                               void* __restrict__ Out3, int M, int N, int K, int lda, int ldb,
                                               int ldc) {
    constexpr int MT = BM / 32;
    __shared__ __align__(16) bf16_t As[BM * 64];
    __shared__ __align__(16) bf16_t Bs[128 * 64];
    const int tid = threadIdx.x;
    const int m0 = blockIdx.y * BM, n0 = blockIdx.x * 128;
    const int lane = tid & 63, wid = tid >> 6;
    const int l16 = lane & 15, quad = lane >> 4;
    const int wm = (wid >> 1) * (BM / 2), wn = (wid & 1) * 64;
    f32x4 acc[MT][4] = {};

    const bf16_t* Ab = A + (size_t)m0 * lda;
    const bf16_t* Bb = Bw + (size_t)n0 * ldb;

    for (int k0 = 0; k0 < K; k0 += 64) {
        __syncthreads();
#pragma unroll
        for (int i = 0; i < BM / 32; ++i) {
            int chunk = tid + i * 256;
            int row = chunk >> 3, col = (chunk & 7) * 8;
            gld_lds16(Ab + (size_t)row * lda + k0 + col, As + row * 64 + col);
        }
#pragma unroll
        for (int i = 0; i < 4; ++i) {
            int chunk = tid + i * 256;
            int row = chunk >> 3, col = (chunk & 7) * 8;
            gld_lds16(Bb + (size_t)row * ldb + k0 + col, Bs + row * 64 + col);
        }
        __syncthreads();
#pragma unroll
        for (int kk = 0; kk < 64; kk += 32) {
            bf16x8 af[MT], bw[4];
#pragma unroll
            for (int mt = 0; mt < MT; ++mt)
                af[mt] = *(const bf16x8*)&As[(wm + mt * 16 + l16) * 64 + kk + quad * 8];
#pragma unroll
            for (int nt = 0; nt < 4; ++nt)
                bw[nt] = *(const bf16x8*)&Bs[(wn + nt * 16 + l16) * 64 + kk + quad * 8];
#pragma unroll
            for (int mt = 0; mt < MT; ++mt)
#pragma unroll
                for (int nt = 0; nt < 4; ++nt) acc[mt][nt] = MFMA16(af[mt], bw[nt], acc[mt][nt]);
        }
    }

#pragma unroll
    for (int mt = 0; mt < MT; ++mt)
#pragma unroll
        for (int nt = 0; nt < 4; ++nt) {
            int n = n0 + wn + nt * 16 + l16;
            float bv = bias ? bias[n] : 0.f;
#pragma unroll
            for (int r = 0; r < 4; ++r) {
                int m = m0 + wm + mt * 16 + quad * 4 + r;
                float v = acc[mt][nt][r] + bv;
                if constexpr (EPI == 2) v = gelu_tanh(v);
                if constexpr (EPI == 0 || EPI == 2) {
                    ((bf16_t*)Out)[(size_t)m * ldc + n] = (bf16_t)v;
                } else if constexpr (EPI == 1) {
                    ((float*)Out)[(size_t)m * ldc + n] = v + res[(size_t)m * ldc + n];
                } else { // EPI 4: qkv split
                    int b = m >> 11, t = m & 2047;
                    if (n < 2048) {
                        int h = (n & 1023) >> 6, d = n & 63;
                        bf16_t* dst = (n < 1024) ? (bf16_t*)Out : (bf16_t*)Out2;
                        dst[(((size_t)b * kH + h) * kT + t) * kD + d] = (bf16_t)v;
                    } else {
                        int n2 = n - 2048;
                        int h = n2 >> 6, d = n2 & 63;
                        ((bf16_t*)Out3)[(((size_t)b * kH + h) * kD + d) * kT + t] = (bf16_t)v;
                    }
                }
            }
        }
}

// ---------------- flash causal self-attention v3 (no-max softmax) ----------------
// q,k: [b,h,t,d] bf16; vT: [b,h,d,t] bf16; sa out: [b,t,c] bf16
__global__ __launch_bounds__(256) void flash_self3(const bf16_t* __restrict__ qb, const bf16_t* __restrict__ kb,
                                                   const bf16_t* __restrict__ vT, bf16_t* __restrict__ sa) {
    const int tid = threadIdx.x;
    const int qi = gridDim.x - 1 - blockIdx.x; // heavy blocks first
    const int h = blockIdx.y, b = blockIdx.z;
    const int lane = tid & 63, wid = tid >> 6;
    const int l16 = lane & 15, quad = lane >> 4;
    const size_t bh = (size_t)b * kH + h;

    __shared__ __align__(16) bf16_t Qs[64 * 64];
    __shared__ __align__(16) bf16_t Ks[64 * 64];
    __shared__ __align__(16) bf16_t VTs[64 * 64];
    bf16_t* Ps = Qs; // reuse after Q frags are hoisted

    const bf16_t* qsrc = qb + (bh * kT + (size_t)qi * 64) * kD;
#pragma unroll
    for (int i = 0; i < 2; ++i) {
        int chunk = tid + i * 256;
        gld_lds16(qsrc + chunk * 8, Qs + chunk * 8);
    }
    __syncthreads();
    bf16x8 aq[2];
    aq[0] = *(const bf16x8*)&Qs[(wid * 16 + l16) * 64 + quad * 8];
    aq[1] = *(const bf16x8*)&Qs[(wid * 16 + l16) * 64 + 32 + quad * 8];
#pragma unroll
    for (int j = 0; j < 8; ++j) { aq[0][j] *= (bf16_t)0.125f; aq[1][j] *= (bf16_t)0.125f; } // exact pow2

    f32x4 o[4] = {};
    float lsum[4] = {0.f, 0.f, 0.f, 0.f};
    const int qrow = qi * 64 + wid * 16 + quad * 4;

    for (int kt = 0; kt <= qi; ++kt) {
        __syncthreads();
        const bf16_t* ksrc = kb + (bh * kT + (size_t)kt * 64) * kD;
        const bf16_t* vsrc = vT + bh * kD * kT + (size_t)kt * 64;
#pragma unroll
        for (int i = 0; i < 2; ++i) {
            int chunk = tid + i * 256;
            gld_lds16(ksrc + chunk * 8, Ks + chunk * 8);
            int row = chunk >> 3, col = (chunk & 7) * 8;
            gld_lds16(vsrc + (size_t)row * kT + col, VTs + chunk * 16ull / 2);
        }
        __syncthreads();

        f32x4 sf[4] = {};
#pragma unroll
        for (int kk = 0; kk < 2; ++kk)
#pragma unroll
            for (int nt = 0; nt < 4; ++nt) {
                bf16x8 bk = *(const bf16x8*)&Ks[(nt * 16 + l16) * 64 + kk * 32 + quad * 8];
                sf[nt] = MFMA16(aq[kk], bk, sf[nt]);
            }

        const bool diag = (kt == qi);
#pragma unroll
        for (int nt = 0; nt < 4; ++nt) {
            int col = kt * 64 + nt * 16 + l16;
#pragma unroll
            for (int r = 0; r < 4; ++r) {
                float s = sf[nt][r];
                if (diag && col > qrow + r) s = -1e30f;
                float p = __expf(s);
                lsum[r] += p;
                Ps[(wid * 16 + quad * 4 + r) * 64 + nt * 16 + l16] = (bf16_t)p;
            }
        }
#pragma unroll
        for (int kk = 0; kk < 2; ++kk) {
            bf16x8 ap = *(const bf16x8*)&Ps[(wid * 16 + l16) * 64 + kk * 32 + quad * 8];
#pragma unroll
            for (int dt = 0; dt < 4; ++dt) {
                bf16x8 bv = *(const bf16x8*)&VTs[(dt * 16 + l16) * 64 + kk * 32 + quad * 8];
                o[dt] = MFMA16(ap, bv, o[dt]);
            }
        }
    }

#pragma unroll
    for (int r = 0; r < 4; ++r) {
        float s = lsum[r];
#pragma unroll
        for (int off = 1; off < 16; off <<= 1) s += __shfl_xor(s, off, 16);
        float inv = 1.f / s;
        size_t row = (size_t)b * kT + qi * 64 + wid * 16 + quad * 4 + r;
#pragma unroll
        for (int dt = 0; dt < 4; ++dt)
            sa[row * kC + h * kD + dt * 16 + l16] = (bf16_t)(o[dt][r] * inv);
    }
}

// ---------------- fused cross-attn: scores + softmax(no-max) + PV ----------------
// q2: [b,t,c] bf16; k2: [b,s,c] bf16; v2T: [b,h,d,s] bf16
// ca out: [b,t,c] bf16; probs out: [b,h,t,s] fp32
__global__ __launch_bounds__(256) void ca_fused(const bf16_t* __restrict__ q2, const bf16_t* __restrict__ k2,
                                                const bf16_t* __restrict__ v2T, bf16_t* __restrict__ ca,
                                                float* __restrict__ probs) {
    const int tid = threadIdx.x;
    const int qi = blockIdx.x, z = blockIdx.y;
    const int b = z >> 4, h = z & 15;
    const int lane = tid & 63, wid = tid >> 6;
    const int l16 = lane & 15, quad = lane >> 4;
    const size_t bh = (size_t)z;

    __shared__ __align__(16) bf16_t Qs[64 * 64];
    __shared__ __align__(16) bf16_t Ks[64 * 64];
    __shared__ __align__(16) bf16_t VTs[64 * 64];
    bf16_t* Ps = Qs;

#pragma unroll
    for (int i = 0; i < 2; ++i) {
        int chunk = tid + i * 256;
        int row = chunk >> 3, col = (chunk & 7) * 8;
        gld_lds16(q2 + ((size_t)(b * kT + qi * 64 + row)) * kC + h * kD + col, Qs + chunk * 8);
    }
    __syncthreads();
    bf16x8 aq[2];
    aq[0] = *(const bf16x8*)&Qs[(wid * 16 + l16) * 64 + quad * 8];
    aq[1] = *(const bf16x8*)&Qs[(wid * 16 + l16) * 64 + 32 + quad * 8];
#pragma unroll
    for (int j = 0; j < 8; ++j) { aq[0][j] *= (bf16_t)0.125f; aq[1][j] *= (bf16_t)0.125f; }

    f32x4 o[4] = {};
    float lsum[4] = {0.f, 0.f, 0.f, 0.f};
    bf16x4 pk[9][4]; // packed P for final probs write (72 VGPRs)

#pragma unroll
    for (int kt = 0; kt < 9; ++kt) {
        __syncthreads();
#pragma unroll
        for (int i = 0; i < 2; ++i) {
            int chunk = tid + i * 256;
            int row = chunk >> 3, col = (chunk & 7) * 8;
            gld_lds16(k2 + ((size_t)(b * kS + kt * 64 + row)) * kC + h * kD + col, Ks + chunk * 8);
            gld_lds16(v2T + (bh * kD + row) * kS + kt * 64 + col, VTs + chunk * 8);
        }
        __syncthreads();

        f32x4 sf[4] = {};
#pragma unroll
        for (int kk = 0; kk < 2; ++kk)
#pragma unroll
            for (int nt = 0; nt < 4; ++nt) {
                bf16x8 bk = *(const bf16x8*)&Ks[(nt * 16 + l16) * 64 + kk * 32 + quad * 8];
                sf[nt] = MFMA16(aq[kk], bk, sf[nt]);
            }
#pragma unroll
        for (int nt = 0; nt < 4; ++nt) {
            bf16x4 pc;
#pragma unroll
            for (int r = 0; r < 4; ++r) {
                float p = __expf(sf[nt][r]);
                lsum[r] += p;
                bf16_t pb = (bf16_t)p;
                pc[r] = pb;
                Ps[(wid * 16 + quad * 4 + r) * 64 + nt * 16 + l16] = pb;
            }
            pk[kt][nt] = pc;
        }
#pragma unroll
        for (int kk = 0; kk < 2; ++kk) {
            bf16x8 ap = *(const bf16x8*)&Ps[(wid * 16 + l16) * 64 + kk * 32 + quad * 8];
#pragma unroll
            for (int dt = 0; dt < 4; ++dt) {
                bf16x8 bv = *(const bf16x8*)&VTs[(dt * 16 + l16) * 64 + kk * 32 + quad * 8];
                o[dt] = MFMA16(ap, bv, o[dt]);
            }
        }
    }

    float inv[4];
#pragma unroll
    for (int r = 0; r < 4; ++r) {
        float s = lsum[r];
#pragma unroll
        for (int off = 1; off < 16; off <<= 1) s += __shfl_xor(s, off, 16);
        inv[r] = 1.f / s;
        size_t row = (size_t)b * kT + qi * 64 + wid * 16 + quad * 4 + r;
#pragma unroll
        for (int dt = 0; dt < 4; ++dt)
            ca[row * kC + h * kD + dt * 16 + l16] = (bf16_t)(o[dt][r] * inv[r]);
    }
    // probs = p * inv  (fp32, [b,h,t,s])
#pragma unroll
    for (int r = 0; r < 4; ++r) {
        float* dst = probs + ((size_t)z * kT + qi * 64 + wid * 16 + quad * 4 + r) * kS;
#pragma unroll
        for (int kt = 0; kt < 9; ++kt)
#pragma unroll
            for (int nt = 0; nt < 4; ++nt)
                dst[kt * 64 + nt * 16 + l16] = (float)pk[kt][nt][r] * inv[r];
    }
}

// ---------------- v2 [B,S,C] -> v2T [B,H,D,S] ----------------
__global__ void v_transpose(const bf16_t* __restrict__ v2, bf16_t* __restrict__ v2T) {
    int idx = blockIdx.x * 256 + threadIdx.x;
    int s = idx % kS;
    int t = idx / kS;
    int d = t % kD; t /= kD;
    int h = t % kH;
    int b = t / kH;
    v2T[idx] = v2[((size_t)(b * kS + s)) * kC + h * kD + d];
}

extern "C" void kernel_launch(void* const* d_in, const int* in_sizes, int n_in, void* d_out, int out_size,
                              void* d_ws, size_t ws_size, hipStream_t stream) {
    const float* x = (const float*)d_in[0];
    const float* context = (const float*)d_in[1];
    const float* ln1_w = (const float*)d_in[2];
    const float* ln1_b = (const float*)d_in[3];
    const float* ln2_w = (const float*)d_in[4];
    const float* ln2_b = (const float*)d_in[5];
    const float* ln3_w = (const float*)d_in[6];
    const float* ln3_b = (const float*)d_in[7];
    const float* attn_wqkv = (const float*)d_in[8];
    const float* attn_bqkv = (const float*)d_in[9];
    const float* attn_wproj = (const float*)d_in[10];
    const float* attn_bproj = (const float*)d_in[11];
    const float* ca_wq = (const float*)d_in[12];
    const float* ca_bq = (const float*)d_in[13];
    const float* ca_wk = (const float*)d_in[14];
    const float* ca_bk = (const float*)d_in[15];
    const float* ca_wv = (const float*)d_in[16];
    const float* ca_bv = (const float*)d_in[17];
    const float* ca_wproj = (const float*)d_in[18];
    const float* ca_bproj = (const float*)d_in[19];
    const float* fc_w = (const float*)d_in[20];
    const float* fc_b = (const float*)d_in[21];
    const float* proj_w = (const float*)d_in[22];
    const float* proj_b = (const float*)d_in[23];

    float* out_x = (float*)d_out;
    float* probs = out_x + (size_t)kB * kT * kC;

    char* wsp = (char*)d_ws;
    size_t off = 0;
    auto alloc = [&](size_t bytes) -> void* {
        void* p = wsp + off;
        off += (bytes + 255) & ~(size_t)255;
        return p;
    };
    bf16_t* wT_qkv   = (bf16_t*)alloc((size_t)3 * kC * kC * 2);
    bf16_t* wT_aproj = (bf16_t*)alloc((size_t)kC * kC * 2);
    bf16_t* wT_caq   = (bf16_t*)alloc((size_t)kC * kC * 2);
    bf16_t* wT_cak   = (bf16_t*)alloc((size_t)kC * kC * 2);
    bf16_t* wT_cav   = (bf16_t*)alloc((size_t)kC * kC * 2);
    bf16_t* wT_caproj= (bf16_t*)alloc((size_t)kC * kC * 2);
    bf16_t* wT_fc    = (bf16_t*)alloc((size_t)4 * kC * kC * 2);
    bf16_t* wT_proj  = (bf16_t*)alloc((size_t)4 * kC * kC * 2);
    bf16_t* hbuf     = (bf16_t*)alloc((size_t)kB * kT * kC * 2);
    bf16_t* qb       = (bf16_t*)alloc((size_t)kB * kT * kC * 2);
    bf16_t* kbuf     = (bf16_t*)alloc((size_t)kB * kT * kC * 2);
    bf16_t* vTb      = (bf16_t*)alloc((size_t)kB * kT * kC * 2);
    bf16_t* sabuf    = (bf16_t*)alloc((size_t)kB * kT * kC * 2);
    float*  x1       = (float*)alloc((size_t)kB * kT * kC * 4);
    float*  x2       = (float*)alloc((size_t)kB * kT * kC * 4);
    bf16_t* ctxb     = (bf16_t*)alloc((size_t)kB * kS * kC * 2);
    bf16_t* q2       = (bf16_t*)alloc((size_t)kB * kT * kC * 2);
    bf16_t* k2       = (bf16_t*)alloc((size_t)kB * kS * kC * 2);
    bf16_t* v2       = (bf16_t*)alloc((size_t)kB * kS * kC * 2);
    bf16_t* v2T      = (bf16_t*)alloc((size_t)kB * kS * kC * 2);
    bf16_t* hf       = (bf16_t*)alloc((size_t)kB * kT * 4 * kC * 2);
    (void)ws_size;

    dim3 tb(32, 8);
    transpose_w<<<dim3(96, 32), tb, 0, stream>>>(attn_wqkv, wT_qkv, kC, 3 * kC);
    transpose_w<<<dim3(32, 32), tb, 0, stream>>>(attn_wproj, wT_aproj, kC, kC);
    transpose_w<<<dim3(32, 32), tb, 0, stream>>>(ca_wq, wT_caq, kC, kC);
    transpose_w<<<dim3(32, 32), tb, 0, stream>>>(ca_wk, wT_cak, kC, kC);
    transpose_w<<<dim3(32, 32), tb, 0, stream>>>(ca_wv, wT_cav, kC, kC);
    transpose_w<<<dim3(32, 32), tb, 0, stream>>>(ca_wproj, wT_caproj, kC, kC);
    transpose_w<<<dim3(128, 32), tb, 0, stream>>>(fc_w, wT_fc, kC, 4 * kC);
    transpose_w<<<dim3(32, 128), tb, 0, stream>>>(proj_w, wT_proj, 4 * kC, kC);
    f32_to_bf16<<<dim3((kB * kS * kC / 4 + 255) / 256), 256, 0, stream>>>(context, ctxb, kB * kS * kC / 4);

    const int Mtok = kB * kT;   // 4096
    // LN1 -> hbuf
    ln_kernel<<<Mtok, 256, 0, stream>>>(x, ln1_w, ln1_b, hbuf);
    // qkv split -> qb [b,h,t,d], kbuf [b,h,t,d], vTb [b,h,d,t]
    gemm128<4, 128><<<dim3(24, 32), 256, 0, stream>>>(hbuf, wT_qkv, attn_bqkv, nullptr, qb, kbuf, vTb, Mtok,
                                                      3 * kC, kC, kC, kC, 0);
    // flash self-attn (no-max)
    flash_self3<<<dim3(kT / 64, kH, kB), 256, 0, stream>>>(qb, kbuf, vTb, sabuf);
    // x1 = x + sa @ Wproj + b
    gemm128<1, 64><<<dim3(8, 64), 256, 0, stream>>>(sabuf, wT_aproj, attn_bproj, x, x1, nullptr, nullptr, Mtok,
                                                    kC, kC, kC, kC, kC);
    // LN2 -> hbuf
    ln_kernel<<<Mtok, 256, 0, stream>>>(x1, ln2_w, ln2_b, hbuf);
    // q2 = h @ Wq + b
    gemm128<0, 64><<<dim3(8, 64), 256, 0, stream>>>(hbuf, wT_caq, ca_bq, nullptr, q2, nullptr, nullptr, Mtok, kC,
                                                    kC, kC, kC, kC);
    // k2 / v2 from context
    gemm128<0, 64><<<dim3(8, 18), 256, 0, stream>>>(ctxb, wT_cak, ca_bk, nullptr, k2, nullptr, nullptr, kB * kS,
                                                    kC, kC, kC, kC, kC);
    gemm128<0, 64><<<dim3(8, 18), 256, 0, stream>>>(ctxb, wT_cav, ca_bv, nullptr, v2, nullptr, nullptr, kB * kS,
                                                    kC, kC, kC, kC, kC);
    v_transpose<<<dim3(kB * kH * kD * kS / 256), 256, 0, stream>>>(v2, v2T);
    // fused cross-attn: scores + softmax + PV -> sabuf (ca), probs (d_out)
    ca_fused<<<dim3(kT / 64, kB * kH), 256, 0, stream>>>(q2, k2, v2T, sabuf, probs);
    // x2 = x1 + ca @ Wcaproj + b
    gemm128<1, 64><<<dim3(8, 64), 256, 0, stream>>>(sabuf, wT_caproj, ca_bproj, x1, x2, nullptr, nullptr, Mtok,
                                                    kC, kC, kC, kC, kC);
    // LN3 -> hbuf
    ln_kernel<<<Mtok, 256, 0, stream>>>(x2, ln3_w, ln3_b, hbuf);
    // hf = gelu(h @ fc_w + b)
    gemm128<2, 128><<<dim3(32, 32), 256, 0, stream>>>(hbuf, wT_fc, fc_b, nullptr, hf, nullptr, nullptr, Mtok,
                                                      4 * kC, kC, kC, kC, 4 * kC);
    // out = x2 + hf @ proj_w + b
    gemm128<1, 64><<<dim3(8, 64), 256, 0, stream>>>(hf, wT_proj, proj_b, x2, out_x, nullptr, nullptr, Mtok, kC,
                                                    4 * kC, 4 * kC, 4 * kC, kC);
}